// Round 18
// baseline (152.207 us; speedup 1.0000x reference)
//
#include <hip/hip_runtime.h>
#include <hip/hip_bf16.h>

#define S_ 2048
#define M_ 8192

typedef __bf16 bf16x8 __attribute__((ext_vector_type(8)));
typedef float f32x4 __attribute__((ext_vector_type(4)));
typedef float f32x16 __attribute__((ext_vector_type(16)));
typedef unsigned int u32x4 __attribute__((ext_vector_type(4)));

__device__ __forceinline__ void gload16(const void* g, void* l) {
  __builtin_amdgcn_global_load_lds(
      (const __attribute__((address_space(1))) void*)g,
      (__attribute__((address_space(3))) void*)l, 16, 0, 0);
}

// single-instruction f32 pair -> packed bf16x2 (low=a, high=b)
__device__ __forceinline__ unsigned int cvtpk(float a, float b) {
  unsigned int r;
  asm("v_cvt_pk_bf16_f32 %0, %1, %2" : "=v"(r) : "v"(a), "v"(b));
  return r;
}

// ---------------- prep: f32 -> bf16 conversions ----------------
__global__ __launch_bounds__(256)
void cvt_x_k(const float* __restrict__ x, __bf16* __restrict__ xb) {
  int i = blockIdx.x * 256 + threadIdx.x;
  float4 v = ((const float4*)x)[i];
  union { __bf16 hh[4]; uint2 u; } pk;
  pk.hh[0] = (__bf16)v.x; pk.hh[1] = (__bf16)v.y;
  pk.hh[2] = (__bf16)v.z; pk.hh[3] = (__bf16)v.w;
  ((uint2*)xb)[i] = pk.u;
}

// W [K][N] f32 -> Wt [N][K] bf16, 64x64 LDS tiles, coalesced both sides
__global__ __launch_bounds__(256)
void tcvt_k(const float* __restrict__ Wm, __bf16* __restrict__ Wt, int K, int N) {
  __shared__ float tile[64][65];
  int nbn = N >> 6;
  int tk = blockIdx.x / nbn, tn = blockIdx.x % nbn;
  int tc = threadIdx.x & 63, tr = threadIdx.x >> 6;
#pragma unroll
  for (int p = 0; p < 16; ++p) {
    int kl = p * 4 + tr;
    tile[kl][tc] = Wm[(size_t)(tk * 64 + kl) * N + tn * 64 + tc];
  }
  __syncthreads();
#pragma unroll
  for (int p = 0; p < 16; ++p) {
    int nl = p * 4 + tr;
    Wt[(size_t)(tn * 64 + nl) * K + tk * 64 + tc] = (__bf16)tile[tc][nl];
  }
}

// ---------------- GEMM: C[M,N] = A[M,K] @ Bt[N,K]^T ----------------
// SERIAL staging (stage -> sync -> compute -> sync): inter-block wave overlap
// hides stage latency (R14: explicit counted-vmcnt dbuf was -5us).
// BM=256: 512 threads, 8 waves (4 row-groups x 2 col-groups), 48KB LDS,
//   2 blocks/CU — halves A-staging per MFMA vs BM=128 (R18).
// BM=128: 256 threads, 4 waves. BM=64: 256 threads, 4 col waves (N=512).
// MODE 0: QKV scatter  MODE 1: f32+bias  MODE 2: bf16+bias+relu  MODE 3: bf16+bias
// KS=2: K-split; partials to outb (ks=0,+bias) / outq (ks=1); LN combines.
template<int MODE, int N, int K, int BM, int KS = 1>
__global__ __launch_bounds__((BM == 256) ? 512 : 256, (BM == 256) ? 4 : 2)
void gemm_k(const __bf16* __restrict__ A, const __bf16* __restrict__ Bt,
            const float* __restrict__ bias,
            float* __restrict__ outf, __bf16* __restrict__ outb,
            __bf16* __restrict__ outq, __bf16* __restrict__ outk,
            __bf16* __restrict__ outv) {
  constexpr int NB = N / 128;
  constexpr int BJ = (BM == 64) ? 2 : 4;    // 16-col frags per wave
  constexpr int KT = K / KS / 64;
  constexpr int TPB = (BM == 256) ? 512 : 256;
  __shared__ __bf16 As[BM * 64];
  __shared__ __bf16 Bs[128 * 64];

  int id = blockIdx.x;
  int cpx = gridDim.x >> 3;                 // grid always a multiple of 8
  int sw = (id & 7) * cpx + (id >> 3);      // XCD-contiguous blocks
  int ks = 0;
  if (KS == 2) { ks = sw & 1; sw >>= 1; }
  int mb = sw / NB, nb = sw % NB;

  int t = threadIdx.x;
  int lane = t & 63;
  int g = lane >> 4, c = lane & 15;
  int w = t >> 6;
  int wrow = (BM == 64) ? 0 : (w >> 1) * 64;
  int wcol = (BM == 64) ? w * 32 : (w & 1) * 64;

  const __bf16* Ab = A + (size_t)mb * BM * K + (size_t)ks * (K / KS);
  const __bf16* Bb = Bt + (size_t)nb * 128 * K + (size_t)ks * (K / KS);

  f32x4 acc[4][BJ] = {};

  for (int kt = 0; kt < KT; ++kt) {
#pragma unroll
    for (int it = 0; it < (BM * 8) / TPB; ++it) {
      int idx = it * TPB + t;
      int row = idx >> 3, ch = idx & 7;
      int sch = ch ^ (row & 7);
      gload16(Ab + (size_t)row * K + kt * 64 + sch * 8, (char*)As + idx * 16);
    }
#pragma unroll
    for (int it = 0; it < 1024 / TPB; ++it) {
      int idx = it * TPB + t;
      int row = idx >> 3, ch = idx & 7;
      int sch = ch ^ (row & 7);
      gload16(Bb + (size_t)row * K + kt * 64 + sch * 8, (char*)Bs + idx * 16);
    }
    __syncthreads();
#pragma unroll
    for (int kk = 0; kk < 2; ++kk) {
      bf16x8 af[4], bfv[BJ];
#pragma unroll
      for (int i = 0; i < 4; ++i) {
        int row = wrow + i * 16 + c;
        int ch = (kk * 4 + g) ^ (row & 7);
        af[i] = *(const bf16x8*)((const char*)As + row * 128 + ch * 16);
      }
#pragma unroll
      for (int j = 0; j < BJ; ++j) {
        int row = wcol + j * 16 + c;
        int ch = (kk * 4 + g) ^ (row & 7);
        bfv[j] = *(const bf16x8*)((const char*)Bs + row * 128 + ch * 16);
      }
      __builtin_amdgcn_s_setprio(1);
#pragma unroll
      for (int i = 0; i < 4; ++i)
#pragma unroll
        for (int j = 0; j < BJ; ++j)
          acc[i][j] = __builtin_amdgcn_mfma_f32_16x16x32_bf16(af[i], bfv[j],
                                                              acc[i][j], 0, 0, 0);
      __builtin_amdgcn_s_setprio(0);
    }
    __syncthreads();
  }

  int row0 = mb * BM + wrow;
  int col0 = nb * 128 + wcol;

  if (MODE == 1) {
#pragma unroll
    for (int j = 0; j < BJ; ++j) {
      int col = col0 + j * 16 + c;
      float bv = bias[col];
#pragma unroll
      for (int i = 0; i < 4; ++i)
#pragma unroll
        for (int r = 0; r < 4; ++r) {
          int rr = row0 + i * 16 + g * 4 + r;
          outf[(size_t)rr * N + col] = acc[i][j][r] + bv;
        }
    }
  } else if (MODE == 2 || MODE == 3) {
    __bf16* dst = (KS == 2 && ks == 1) ? outq : outb;
#pragma unroll
    for (int j = 0; j < BJ; ++j) {
      int col = col0 + j * 16 + c;
      float bv = (KS == 2 && ks == 1) ? 0.f : bias[col];
#pragma unroll
      for (int i = 0; i < 4; ++i)
#pragma unroll
        for (int r = 0; r < 4; ++r) {
          int rr = row0 + i * 16 + g * 4 + r;
          float v = acc[i][j][r] + bv;
          if (MODE == 2) v = fmaxf(v, 0.f);
          dst[(size_t)rr * N + col] = (__bf16)v;
        }
    }
  } else {  // QKV scatter (KS==1 only)
    int tsel = nb >> 2;                    // 0:Q 1:K 2:V (uniform per block)
    int h = ((nb & 3) << 1) | (w & 1);     // uniform per wave
#pragma unroll
    for (int j = 0; j < BJ; ++j) {
      int hd = j * 16 + c;
      float bv = bias[nb * 128 + wcol + j * 16 + c];
#pragma unroll
      for (int i = 0; i < 4; ++i) {
        int rr = row0 + i * 16 + g * 4;    // 4 consecutive rows
        int b = rr >> 11, s = rr & 2047;
        int bh = b * 8 + h;
        if (tsel == 2) {
          union { __bf16 hh[4]; uint2 u; } pk;
#pragma unroll
          for (int r = 0; r < 4; ++r) pk.hh[r] = (__bf16)(acc[i][j][r] + bv);
          *(uint2*)(outv + ((size_t)bh * 64 + hd) * 2048 + s) = pk.u;
        } else {
          __bf16* dst = (tsel == 0 ? outq : outk);
#pragma unroll
          for (int r = 0; r < 4; ++r)
            dst[((size_t)bh * 2048 + s + r) * 64 + hd] = (__bf16)(acc[i][j][r] + bv);
        }
      }
    }
  }
}

// ---------------- flash attention: 32x32 MFMA, in-register P (T12) ----------------
// q,k: [bh][s][64] bf16, vt: [bh][64][s] bf16 -> ctx: [b][s][h*64+d] bf16
// 4 waves = 2(q-group of 32) x 2(k-half of 32). Swapped QK via
// mfma_32x32x16(K,Q): C col=q=lane&31, rows=32 k's in 16 regs. Static
// softmax: P = raw v_exp_f32(S) in regs (|s|<~25 -> no OCML guards needed);
// pack via v_cvt_pk_bf16_f32 (1 inst/pair) + v_permlane32_swap_b32 ->
// PV A-fragments with ZERO P-LDS traffic. k-halves combined via LDS at
// epilogue (additive under static softmax). LDS 33KB -> 4 blocks/CU.
__global__ __launch_bounds__(256, 4)
void attn_k(const __bf16* __restrict__ qb, const __bf16* __restrict__ kb,
            const __bf16* __restrict__ vt, __bf16* __restrict__ ctx) {
  __shared__ __bf16 Ks[2][64 * 64];     // [k][d], chunk-swizzled by k&7
  __shared__ __bf16 Vs[2][64 * 64];     // [d][k], chunk-swizzled by d&7
  __shared__ float srun_l[64];          // [wq*32 + q]

  int id = blockIdx.x;
  int sw = (id & 7) * 128 + (id >> 3);  // XCD-contiguous
  int bh = sw >> 5, qblk = sw & 31;

  int t = threadIdx.x, lane = t & 63, w = t >> 6;
  int c32 = lane & 31, h = lane >> 5;
  int wq = w >> 1, wk = w & 1;

  const __bf16* Q  = qb + (size_t)bh * S_ * 64;
  const __bf16* Kp = kb + (size_t)bh * S_ * 64;
  const __bf16* Vp = vt + (size_t)bh * 64 * S_;

  int q0 = qblk * 64;
  int qg = q0 + wq * 32 + c32;          // this lane's q (B-operand col)

  // Q B-fragments: lane col=q, contraction d = c16*16 + h*8 + e;
  // pre-scaled by 0.125 * log2(e)
  bf16x8 qf[4];
#pragma unroll
  for (int c16 = 0; c16 < 4; ++c16) {
    bf16x8 v = *(const bf16x8*)(Q + (size_t)qg * 64 + c16 * 16 + h * 8);
#pragma unroll
    for (int e = 0; e < 8; ++e) v[e] = (__bf16)((float)v[e] * 0.18033688f);
    qf[c16] = v;
  }

  f32x16 o0 = {}, o1 = {};              // O[q-rows][d 0-31], [d 32-63]
  float srun = 0.f;

  int swz = c32 & 7;
  int krowb = (wk * 32 + c32) * 128;    // K A-frag: row = wave's k-half + c32
  int kchunk[4];
#pragma unroll
  for (int c16 = 0; c16 < 4; ++c16)
    kchunk[c16] = (((c16 * 2 + h)) ^ swz) * 16;
  int vchunk[2];                        // V B-frag: k = wk*32 + kc*16 + h*8
#pragma unroll
  for (int kc = 0; kc < 2; ++kc)
    vchunk[kc] = ((wk * 4 + kc * 2 + h) ^ swz) * 16;

  // cooperative stage of k-tile kt into buffer buf (8KB K + 8KB V): 4 VMEM/thread
  auto stage = [&](int kt, int buf) {
    int kbase = kt * 64;
#pragma unroll
    for (int it = 0; it < 2; ++it) {
      int idx = it * 256 + t;          // 0..511 chunks of 16B
      int row = idx >> 3, ch = idx & 7;
      int sch = ch ^ (row & 7);        // pre-swizzled global source
      gload16(Kp + (size_t)(kbase + row) * 64 + sch * 8, (char*)Ks[buf] + idx * 16);
      gload16(Vp + (size_t)row * S_ + kbase + sch * 8,   (char*)Vs[buf] + idx * 16);
    }
  };

  stage(0, 0);

  auto step = [&](int kbi, int cur, bool last) {
    if (!last) stage(kbi + 1, cur ^ 1);   // 4 VMEM, stay in flight past barrier
    if (last) asm volatile("s_waitcnt vmcnt(0)" ::: "memory");
    else      asm volatile("s_waitcnt vmcnt(4)" ::: "memory");  // tile kbi landed
    __builtin_amdgcn_s_barrier();         // all waves' tile kbi landed
    asm volatile("" ::: "memory");
    const char* Kb = (const char*)Ks[cur];
    const char* Vb = (const char*)Vs[cur];

    // --- QK^T swapped: one 32x32 C-tile per wave (rows=k, cols=q) ---
    f32x16 sacc = {};
    __builtin_amdgcn_s_setprio(1);
#pragma unroll
    for (int c16 = 0; c16 < 4; ++c16) {
      bf16x8 kf = *(const bf16x8*)(Kb + krowb + kchunk[c16]);
      sacc = __builtin_amdgcn_mfma_f32_32x32x16_bf16(kf, qf[c16], sacc, 0, 0, 0);
    }
    __builtin_amdgcn_s_setprio(0);

    // --- static softmax in-register: raw v_exp_f32 (domain-safe) ---
    float p[16];
#pragma unroll
    for (int i = 0; i < 16; ++i) { p[i] = __builtin_amdgcn_exp2f(sacc[i]); }
#pragma unroll
    for (int i = 0; i < 16; i += 4)
      srun += ((p[i] + p[i + 1]) + (p[i + 2] + p[i + 3]));

    // --- P -> PV A-fragments (v_cvt_pk_bf16_f32 + permlane32_swap, T12) ---
    unsigned int x1 = cvtpk(p[0], p[1]),  x2 = cvtpk(p[2], p[3]);
    unsigned int y1 = cvtpk(p[4], p[5]),  y2 = cvtpk(p[6], p[7]);
    asm volatile("v_permlane32_swap_b32 %0, %1" : "+v"(y1), "+v"(x1));
    asm volatile("v_permlane32_swap_b32 %0, %1" : "+v"(y2), "+v"(x2));
    u32x4 f0 = {x1, x2, y1, y2};
    bf16x8 pa0 = __builtin_bit_cast(bf16x8, f0);
    unsigned int x3 = cvtpk(p[8], p[9]),   x4 = cvtpk(p[10], p[11]);
    unsigned int y3 = cvtpk(p[12], p[13]), y4 = cvtpk(p[14], p[15]);
    asm volatile("v_permlane32_swap_b32 %0, %1" : "+v"(y3), "+v"(x3));
    asm volatile("v_permlane32_swap_b32 %0, %1" : "+v"(y4), "+v"(x4));
    u32x4 f1 = {x3, x4, y3, y4};
    bf16x8 pa1 = __builtin_bit_cast(bf16x8, f1);

    // --- PV: A=P (regs), B=V from LDS ---
    __builtin_amdgcn_s_setprio(1);
#pragma unroll
    for (int kc = 0; kc < 2; ++kc) {
      bf16x8 pa = kc ? pa1 : pa0;
      bf16x8 va = *(const bf16x8*)(Vb + c32 * 128 + vchunk[kc]);
      bf16x8 vb = *(const bf16x8*)(Vb + (32 + c32) * 128 + vchunk[kc]);
      o0 = __builtin_amdgcn_mfma_f32_32x32x16_bf16(pa, va, o0, 0, 0, 0);
      o1 = __builtin_amdgcn_mfma_f32_32x32x16_bf16(pa, vb, o1, 0, 0, 0);
    }
    __builtin_amdgcn_s_setprio(0);

    if (!last) {
      asm volatile("" ::: "memory");      // all reads issued before the barrier
      __builtin_amdgcn_s_barrier();       // reads of buf cur done in all waves
      asm volatile("" ::: "memory");
    }
  };

  for (int kbi = 0; kbi < 30; kbi += 2) {
    step(kbi, 0, false);
    step(kbi + 1, 1, false);
  }
  step(30, 0, false);
  step(31, 1, true);

  // ---- epilogue: combine k-half waves via LDS, normalize, write ----
  srun += __shfl_xor(srun, 32);           // full 32-k sum per q=c32
  __syncthreads();                        // all K/V reads done; Ks reusable
  float* olds = (float*)Ks;               // 16KB: [wq][32 q][64 d]
  if (wk == 1) {
#pragma unroll
    for (int reg = 0; reg < 16; ++reg) {
      int qrow = (reg & 3) + 8 * (reg >> 2) + 4 * h;
      olds[wq * 2048 + qrow * 64 + c32]      = o0[reg];
      olds[wq * 2048 + qrow * 64 + 32 + c32] = o1[reg];
    }
    srun_l[wq * 32 + c32] = srun;
  }
  __syncthreads();
  if (wk == 0) {
    float stot = srun + srun_l[wq * 32 + c32];
    int b = bh >> 3, hd = bh & 7;
#pragma unroll
    for (int reg = 0; reg < 16; ++reg) {
      int qrow = (reg & 3) + 8 * (reg >> 2) + 4 * h;
      float inv = 1.f / __shfl(stot, qrow);
      float s0 = o0[reg] + olds[wq * 2048 + qrow * 64 + c32];
      float s1 = o1[reg] + olds[wq * 2048 + qrow * 64 + 32 + c32];
      int qg2 = q0 + wq * 32 + qrow;
      size_t base = ((size_t)(b * 2048 + qg2)) * 512 + hd * 64;
      ctx[base + c32]      = (__bf16)(s0 * inv);
      ctx[base + 32 + c32] = (__bf16)(s1 * inv);
    }
  }
}

// ---------------- LayerNorm (residual add fused) ----------------
// IN1F32: in1 is f32 (else bf16). WF: write f32 out (else bf16 out).
// IN3: add a third input (bf16 partial from K-split GEMM).
template<bool IN1F32, bool WF, bool IN3>
__global__ __launch_bounds__(256)
void ln_k(const float* __restrict__ in1f, const __bf16* __restrict__ in1b,
          const __bf16* __restrict__ in2, const __bf16* __restrict__ in3,
          const float* __restrict__ gam, const float* __restrict__ bet,
          float* __restrict__ outf, __bf16* __restrict__ outb) {
  int w = threadIdx.x >> 6, lane = threadIdx.x & 63;
  int row = blockIdx.x * 4 + w;
  size_t base = (size_t)row * 512 + lane * 8;
  float a[8];
  if (IN1F32) {
    float4 a0 = *(const float4*)(in1f + base);
    float4 a1 = *(const float4*)(in1f + base + 4);
    a[0] = a0.x; a[1] = a0.y; a[2] = a0.z; a[3] = a0.w;
    a[4] = a1.x; a[5] = a1.y; a[6] = a1.z; a[7] = a1.w;
  } else {
    bf16x8 av = *(const bf16x8*)(in1b + base);
#pragma unroll
    for (int k = 0; k < 8; ++k) a[k] = (float)av[k];
  }
  bf16x8 bv = *(const bf16x8*)(in2 + base);
  float x[8];
#pragma unroll
  for (int k = 0; k < 8; ++k) x[k] = a[k] + (float)bv[k];
  if (IN3) {
    bf16x8 cv = *(const bf16x8*)(in3 + base);
#pragma unroll
    for (int k = 0; k < 8; ++k) x[k] += (float)cv[k];
  }
  float s1 = 0.f, s2 = 0.f;
#pragma unroll
  for (int k = 0; k < 8; ++k) { s1 += x[k]; s2 += x[k] * x[k]; }
#pragma unroll
  for (int m = 1; m < 64; m <<= 1) { s1 += __shfl_xor(s1, m); s2 += __shfl_xor(s2, m); }
  float mu = s1 * (1.f / 512.f);
  float var = s2 * (1.f / 512.f) - mu * mu;
  float rs = rsqrtf(var + 1e-5f);
  float4 g0 = *(const float4*)(gam + lane * 8);
  float4 g1 = *(const float4*)(gam + lane * 8 + 4);
  float4 e0 = *(const float4*)(bet + lane * 8);
  float4 e1 = *(const float4*)(bet + lane * 8 + 4);
  float gg[8] = {g0.x, g0.y, g0.z, g0.w, g1.x, g1.y, g1.z, g1.w};
  float bb[8] = {e0.x, e0.y, e0.z, e0.w, e1.x, e1.y, e1.z, e1.w};
  float y[8];
#pragma unroll
  for (int k = 0; k < 8; ++k) y[k] = (x[k] - mu) * rs * gg[k] + bb[k];
  if (WF) {
    float4 o0 = {y[0], y[1], y[2], y[3]};
    float4 o1 = {y[4], y[5], y[6], y[7]};
    *(float4*)(outf + base) = o0;
    *(float4*)(outf + base + 4) = o1;
  } else {
    union { __bf16 hh[8]; uint4 u; } pk;
#pragma unroll
    for (int k = 0; k < 8; ++k) pk.hh[k] = (__bf16)y[k];
    *(uint4*)(outb + base) = pk.u;
  }
}

extern "C" void kernel_launch(void* const* d_in, const int* in_sizes, int n_in,
                              void* d_out, int out_size, void* d_ws, size_t ws_size,
                              hipStream_t stream) {
  (void)in_sizes; (void)n_in; (void)out_size;
  const float* x    = (const float*)d_in[0];
  const float* Wqkv = (const float*)d_in[1];
  const float* bqkv = (const float*)d_in[2];
  const float* Wo   = (const float*)d_in[3];
  const float* bo   = (const float*)d_in[4];
  const float* g1   = (const float*)d_in[5];
  const float* be1  = (const float*)d_in[6];
  const float* W1   = (const float*)d_in[7];
  const float* b1   = (const float*)d_in[8];
  const float* W2   = (const float*)d_in[9];
  const float* b2   = (const float*)d_in[10];
  const float* g2   = (const float*)d_in[11];
  const float* be2  = (const float*)d_in[12];
  float* out = (float*)d_out;

  char* ws = (char*)d_ws;
  size_t off = 0;
  auto alloc = [&](size_t bytes) {
    char* p = ws + off;
    off += (bytes + 255) & ~(size_t)255;
    return p;
  };
  __bf16* xb    = (__bf16*)alloc((size_t)M_ * 512 * 2);
  __bf16* wqkvt = (__bf16*)alloc((size_t)1536 * 512 * 2);
  __bf16* wot   = (__bf16*)alloc((size_t)512 * 512 * 2);
  __bf16* w1t   = (__bf16*)alloc((size_t)2048 * 512 * 2);
  __bf16* w2t   = (__bf16*)alloc((size_t)512 * 2048 * 2);
  __bf16* qbuf  = (__bf16*)alloc((size_t)32 * 2048 * 64 * 2);
  __bf16* kbuf  = (__bf16*)alloc((size_t)32 * 2048 * 64 * 2);
  __bf16* vtbuf = (__bf16*)alloc((size_t)32 * 64 * 2048 * 2);
  __bf16* ctxb  = (__bf16*)alloc((size_t)M_ * 512 * 2);
  __bf16* part0 = (__bf16*)alloc((size_t)M_ * 512 * 2);   // K-split partial 0
  __bf16* part1 = (__bf16*)alloc((size_t)M_ * 512 * 2);   // K-split partial 1
  __bf16* y1b   = (__bf16*)alloc((size_t)M_ * 512 * 2);
  __bf16* h1    = (__bf16*)alloc((size_t)M_ * 2048 * 2);
  if (off > ws_size) return;  // workspace too small: fail loudly (wrong output)

  cvt_x_k<<<4096, 256, 0, stream>>>(x, xb);
  tcvt_k<<<192, 256, 0, stream>>>(Wqkv, wqkvt, 512, 1536);
  tcvt_k<<<64, 256, 0, stream>>>(Wo, wot, 512, 512);
  tcvt_k<<<256, 256, 0, stream>>>(W1, w1t, 512, 2048);
  tcvt_k<<<256, 256, 0, stream>>>(W2, w2t, 2048, 512);

  // qkv + ffn1: BM=256 tiles (512 threads, 8 waves)
  gemm_k<0, 1536, 512, 256><<<384, 512, 0, stream>>>(xb, wqkvt, bqkv, nullptr, nullptr,
                                                     qbuf, kbuf, vtbuf);
  attn_k<<<1024, 256, 0, stream>>>(qbuf, kbuf, vtbuf, ctxb);
  // wo: 2-way K-split, partials combined in LN1
  gemm_k<3, 512, 512, 64, 2><<<1024, 256, 0, stream>>>(ctxb, wot, bo, nullptr, part0,
                                                       part1, nullptr, nullptr);
  ln_k<true, false, true><<<2048, 256, 0, stream>>>(x, nullptr, part0, part1, g1, be1,
                                                    nullptr, y1b);
  gemm_k<2, 2048, 512, 256><<<512, 512, 0, stream>>>(y1b, w1t, b1, nullptr, h1,
                                                     nullptr, nullptr, nullptr);
  // ffn2: 2-way K-split, partials combined in LN2 (part0/1 dead after LN1)
  gemm_k<3, 512, 2048, 64, 2><<<1024, 256, 0, stream>>>(h1, w2t, b2, nullptr, part0,
                                                        part1, nullptr, nullptr);
  ln_k<false, true, true><<<2048, 256, 0, stream>>>(nullptr, y1b, part0, part1, g2, be2,
                                                    out, nullptr);
}

// Round 19
// 142.759 us; speedup vs baseline: 1.0662x; 1.0662x over previous
//
#include <hip/hip_runtime.h>
#include <hip/hip_bf16.h>

#define S_ 2048
#define M_ 8192

typedef __bf16 bf16x8 __attribute__((ext_vector_type(8)));
typedef float f32x4 __attribute__((ext_vector_type(4)));
typedef float f32x16 __attribute__((ext_vector_type(16)));
typedef unsigned int u32x4 __attribute__((ext_vector_type(4)));

__device__ __forceinline__ void gload16(const void* g, void* l) {
  __builtin_amdgcn_global_load_lds(
      (const __attribute__((address_space(1))) void*)g,
      (__attribute__((address_space(3))) void*)l, 16, 0, 0);
}

// single-instruction f32 pair -> packed bf16x2 (low=a, high=b)
__device__ __forceinline__ unsigned int cvtpk(float a, float b) {
  unsigned int r;
  asm("v_cvt_pk_bf16_f32 %0, %1, %2" : "=v"(r) : "v"(a), "v"(b));
  return r;
}

// ---------------- prep: f32 -> bf16 conversions ----------------
__global__ __launch_bounds__(256)
void cvt_x_k(const float* __restrict__ x, __bf16* __restrict__ xb) {
  int i = blockIdx.x * 256 + threadIdx.x;
  float4 v = ((const float4*)x)[i];
  union { __bf16 hh[4]; uint2 u; } pk;
  pk.hh[0] = (__bf16)v.x; pk.hh[1] = (__bf16)v.y;
  pk.hh[2] = (__bf16)v.z; pk.hh[3] = (__bf16)v.w;
  ((uint2*)xb)[i] = pk.u;
}

// ALL four weight transposes in ONE launch: W [K][N] f32 -> Wt [N][K] bf16.
// Block ranges: [0,192) Wqkv; [192,256) Wo; [256,512) W1; [512,768) W2.
__global__ __launch_bounds__(256)
void tcvt_all_k(const float* __restrict__ Wqkv, const float* __restrict__ Wo,
                const float* __restrict__ W1, const float* __restrict__ W2,
                __bf16* __restrict__ wqkvt, __bf16* __restrict__ wot,
                __bf16* __restrict__ w1t, __bf16* __restrict__ w2t) {
  __shared__ float tile[64][65];
  int bid = blockIdx.x;
  const float* Wm; __bf16* Wt; int K, N, lb;
  if (bid < 192)      { Wm = Wqkv; Wt = wqkvt; K = 512;  N = 1536; lb = 0; }
  else if (bid < 256) { Wm = Wo;   Wt = wot;   K = 512;  N = 512;  lb = 192; }
  else if (bid < 512) { Wm = W1;   Wt = w1t;   K = 512;  N = 2048; lb = 256; }
  else                { Wm = W2;   Wt = w2t;   K = 2048; N = 512;  lb = 512; }
  int lid = bid - lb;
  int nbn = N >> 6;
  int tk = lid / nbn, tn = lid % nbn;
  int tc = threadIdx.x & 63, tr = threadIdx.x >> 6;
#pragma unroll
  for (int p = 0; p < 16; ++p) {
    int kl = p * 4 + tr;
    tile[kl][tc] = Wm[(size_t)(tk * 64 + kl) * N + tn * 64 + tc];
  }
  __syncthreads();
#pragma unroll
  for (int p = 0; p < 16; ++p) {
    int nl = p * 4 + tr;
    Wt[(size_t)(tn * 64 + nl) * K + tk * 64 + tc] = (__bf16)tile[tc][nl];
  }
}

// ---------------- GEMM: C[M,N] = A[M,K] @ Bt[N,K]^T ----------------
// SERIAL staging (stage -> sync -> compute -> sync): inter-block wave overlap
// hides stage latency (R14: counted-vmcnt dbuf -5us; R18: BM=256 +3us —
// this 2-barrier loop prefers BM=128/4-wave).
// MODE 0: QKV scatter  MODE 1: f32+bias  MODE 2: bf16+bias+relu  MODE 3: bf16+bias
// KS=2: K-split; partials to outb (ks=0,+bias) / outq (ks=1); LN combines.
template<int MODE, int N, int K, int BM, int KS = 1>
__global__ __launch_bounds__(256, 2)
void gemm_k(const __bf16* __restrict__ A, const __bf16* __restrict__ Bt,
            const float* __restrict__ bias,
            float* __restrict__ outf, __bf16* __restrict__ outb,
            __bf16* __restrict__ outq, __bf16* __restrict__ outk,
            __bf16* __restrict__ outv) {
  constexpr int NB = N / 128;
  constexpr int BJ = (BM == 128) ? 4 : 2;   // 16-col frags per wave
  constexpr int KT = K / KS / 64;
  __shared__ __bf16 As[BM * 64];
  __shared__ __bf16 Bs[128 * 64];

  int id = blockIdx.x;
  int cpx = gridDim.x >> 3;                 // grid always a multiple of 8
  int sw = (id & 7) * cpx + (id >> 3);      // XCD-contiguous blocks
  int ks = 0;
  if (KS == 2) { ks = sw & 1; sw >>= 1; }
  int mb = sw / NB, nb = sw % NB;

  int t = threadIdx.x;
  int lane = t & 63;
  int g = lane >> 4, c = lane & 15;
  int w = t >> 6;
  int wrow = (BM == 128) ? (w >> 1) * 64 : 0;
  int wcol = (BM == 128) ? (w & 1) * 64 : w * 32;

  const __bf16* Ab = A + (size_t)mb * BM * K + (size_t)ks * (K / KS);
  const __bf16* Bb = Bt + (size_t)nb * 128 * K + (size_t)ks * (K / KS);

  f32x4 acc[4][BJ] = {};

  for (int kt = 0; kt < KT; ++kt) {
#pragma unroll
    for (int it = 0; it < BM / 32; ++it) {
      int idx = it * 256 + t;
      int row = idx >> 3, ch = idx & 7;
      int sch = ch ^ (row & 7);
      gload16(Ab + (size_t)row * K + kt * 64 + sch * 8, (char*)As + idx * 16);
    }
#pragma unroll
    for (int it = 0; it < 4; ++it) {
      int idx = it * 256 + t;
      int row = idx >> 3, ch = idx & 7;
      int sch = ch ^ (row & 7);
      gload16(Bb + (size_t)row * K + kt * 64 + sch * 8, (char*)Bs + idx * 16);
    }
    __syncthreads();
#pragma unroll
    for (int kk = 0; kk < 2; ++kk) {
      bf16x8 af[4], bfv[BJ];
#pragma unroll
      for (int i = 0; i < 4; ++i) {
        int row = wrow + i * 16 + c;
        int ch = (kk * 4 + g) ^ (row & 7);
        af[i] = *(const bf16x8*)((const char*)As + row * 128 + ch * 16);
      }
#pragma unroll
      for (int j = 0; j < BJ; ++j) {
        int row = wcol + j * 16 + c;
        int ch = (kk * 4 + g) ^ (row & 7);
        bfv[j] = *(const bf16x8*)((const char*)Bs + row * 128 + ch * 16);
      }
      __builtin_amdgcn_s_setprio(1);
#pragma unroll
      for (int i = 0; i < 4; ++i)
#pragma unroll
        for (int j = 0; j < BJ; ++j)
          acc[i][j] = __builtin_amdgcn_mfma_f32_16x16x32_bf16(af[i], bfv[j],
                                                              acc[i][j], 0, 0, 0);
      __builtin_amdgcn_s_setprio(0);
    }
    __syncthreads();
  }

  int row0 = mb * BM + wrow;
  int col0 = nb * 128 + wcol;

  if (MODE == 1) {
#pragma unroll
    for (int j = 0; j < BJ; ++j) {
      int col = col0 + j * 16 + c;
      float bv = bias[col];
#pragma unroll
      for (int i = 0; i < 4; ++i)
#pragma unroll
        for (int r = 0; r < 4; ++r) {
          int rr = row0 + i * 16 + g * 4 + r;
          outf[(size_t)rr * N + col] = acc[i][j][r] + bv;
        }
    }
  } else if (MODE == 2 || MODE == 3) {
    __bf16* dst = (KS == 2 && ks == 1) ? outq : outb;
#pragma unroll
    for (int j = 0; j < BJ; ++j) {
      int col = col0 + j * 16 + c;
      float bv = (KS == 2 && ks == 1) ? 0.f : bias[col];
#pragma unroll
      for (int i = 0; i < 4; ++i)
#pragma unroll
        for (int r = 0; r < 4; ++r) {
          int rr = row0 + i * 16 + g * 4 + r;
          float v = acc[i][j][r] + bv;
          if (MODE == 2) v = fmaxf(v, 0.f);
          dst[(size_t)rr * N + col] = (__bf16)v;
        }
    }
  } else {  // QKV scatter (BM==128, KS==1 only)
    int tsel = nb >> 2;                    // 0:Q 1:K 2:V (uniform per block)
    int h = ((nb & 3) << 1) | (w & 1);     // uniform per wave
#pragma unroll
    for (int j = 0; j < BJ; ++j) {
      int hd = j * 16 + c;
      float bv = bias[nb * 128 + wcol + j * 16 + c];
#pragma unroll
      for (int i = 0; i < 4; ++i) {
        int rr = row0 + i * 16 + g * 4;    // 4 consecutive rows
        int b = rr >> 11, s = rr & 2047;
        int bh = b * 8 + h;
        if (tsel == 2) {
          union { __bf16 hh[4]; uint2 u; } pk;
#pragma unroll
          for (int r = 0; r < 4; ++r) pk.hh[r] = (__bf16)(acc[i][j][r] + bv);
          *(uint2*)(outv + ((size_t)bh * 64 + hd) * 2048 + s) = pk.u;
        } else {
          __bf16* dst = (tsel == 0 ? outq : outk);
#pragma unroll
          for (int r = 0; r < 4; ++r)
            dst[((size_t)bh * 2048 + s + r) * 64 + hd] = (__bf16)(acc[i][j][r] + bv);
        }
      }
    }
  }
}

// ---------------- flash attention: 32x32 MFMA, in-register P (T12) ----------------
// q,k: [bh][s][64] bf16, vt: [bh][64][s] bf16 -> ctx: [b][s][h*64+d] bf16
// 4 waves = 2(q-group of 32) x 2(k-half of 32). Swapped QK via
// mfma_32x32x16(K,Q): C col=q=lane&31, rows=32 k's in 16 regs. Static
// softmax: P = raw v_exp_f32(S) in regs (|s|<~25 -> no OCML guards needed);
// pack via v_cvt_pk_bf16_f32 (1 inst/pair) + v_permlane32_swap_b32 ->
// PV A-fragments with ZERO P-LDS traffic. k-halves combined via LDS at
// epilogue (additive under static softmax). LDS 33KB -> 4 blocks/CU.
__global__ __launch_bounds__(256, 4)
void attn_k(const __bf16* __restrict__ qb, const __bf16* __restrict__ kb,
            const __bf16* __restrict__ vt, __bf16* __restrict__ ctx) {
  __shared__ __bf16 Ks[2][64 * 64];     // [k][d], chunk-swizzled by k&7
  __shared__ __bf16 Vs[2][64 * 64];     // [d][k], chunk-swizzled by d&7
  __shared__ float srun_l[64];          // [wq*32 + q]

  int id = blockIdx.x;
  int sw = (id & 7) * 128 + (id >> 3);  // XCD-contiguous
  int bh = sw >> 5, qblk = sw & 31;

  int t = threadIdx.x, lane = t & 63, w = t >> 6;
  int c32 = lane & 31, h = lane >> 5;
  int wq = w >> 1, wk = w & 1;

  const __bf16* Q  = qb + (size_t)bh * S_ * 64;
  const __bf16* Kp = kb + (size_t)bh * S_ * 64;
  const __bf16* Vp = vt + (size_t)bh * 64 * S_;

  int q0 = qblk * 64;
  int qg = q0 + wq * 32 + c32;          // this lane's q (B-operand col)

  // Q B-fragments: lane col=q, contraction d = c16*16 + h*8 + e;
  // pre-scaled by 0.125 * log2(e)
  bf16x8 qf[4];
#pragma unroll
  for (int c16 = 0; c16 < 4; ++c16) {
    bf16x8 v = *(const bf16x8*)(Q + (size_t)qg * 64 + c16 * 16 + h * 8);
#pragma unroll
    for (int e = 0; e < 8; ++e) v[e] = (__bf16)((float)v[e] * 0.18033688f);
    qf[c16] = v;
  }

  f32x16 o0 = {}, o1 = {};              // O[q-rows][d 0-31], [d 32-63]
  float srun = 0.f;

  int swz = c32 & 7;
  int krowb = (wk * 32 + c32) * 128;    // K A-frag: row = wave's k-half + c32
  int kchunk[4];
#pragma unroll
  for (int c16 = 0; c16 < 4; ++c16)
    kchunk[c16] = (((c16 * 2 + h)) ^ swz) * 16;
  int vchunk[2];                        // V B-frag: k = wk*32 + kc*16 + h*8
#pragma unroll
  for (int kc = 0; kc < 2; ++kc)
    vchunk[kc] = ((wk * 4 + kc * 2 + h) ^ swz) * 16;

  // cooperative stage of k-tile kt into buffer buf (8KB K + 8KB V): 4 VMEM/thread
  auto stage = [&](int kt, int buf) {
    int kbase = kt * 64;
#pragma unroll
    for (int it = 0; it < 2; ++it) {
      int idx = it * 256 + t;          // 0..511 chunks of 16B
      int row = idx >> 3, ch = idx & 7;
      int sch = ch ^ (row & 7);        // pre-swizzled global source
      gload16(Kp + (size_t)(kbase + row) * 64 + sch * 8, (char*)Ks[buf] + idx * 16);
      gload16(Vp + (size_t)row * S_ + kbase + sch * 8,   (char*)Vs[buf] + idx * 16);
    }
  };

  stage(0, 0);

  auto step = [&](int kbi, int cur, bool last) {
    if (!last) stage(kbi + 1, cur ^ 1);   // 4 VMEM, stay in flight past barrier
    if (last) asm volatile("s_waitcnt vmcnt(0)" ::: "memory");
    else      asm volatile("s_waitcnt vmcnt(4)" ::: "memory");  // tile kbi landed
    __builtin_amdgcn_s_barrier();         // all waves' tile kbi landed
    asm volatile("" ::: "memory");
    const char* Kb = (const char*)Ks[cur];
    const char* Vb = (const char*)Vs[cur];

    // --- QK^T swapped: one 32x32 C-tile per wave (rows=k, cols=q) ---
    f32x16 sacc = {};
    __builtin_amdgcn_s_setprio(1);
#pragma unroll
    for (int c16 = 0; c16 < 4; ++c16) {
      bf16x8 kf = *(const bf16x8*)(Kb + krowb + kchunk[c16]);
      sacc = __builtin_amdgcn_mfma_f32_32x32x16_bf16(kf, qf[c16], sacc, 0, 0, 0);
    }
    __builtin_amdgcn_s_setprio(0);

    // --- static softmax in-register: raw v_exp_f32 (domain-safe) ---
    float p[16];
#pragma unroll
    for (int i = 0; i < 16; ++i) { p[i] = __builtin_amdgcn_exp2f(sacc[i]); }
#pragma unroll
    for (int i = 0; i < 16; i += 4)
      srun += ((p[i] + p[i + 1]) + (p[i + 2] + p[i + 3]));

    // --- P -> PV A-fragments (v_cvt_pk_bf16_f32 + permlane32_swap, T12) ---
    unsigned int x1 = cvtpk(p[0], p[1]),  x2 = cvtpk(p[2], p[3]);
    unsigned int y1 = cvtpk(p[4], p[5]),  y2 = cvtpk(p[6], p[7]);
    asm volatile("v_permlane32_swap_b32 %0, %1" : "+v"(y1), "+v"(x1));
    asm volatile("v_permlane32_swap_b32 %0, %1" : "+v"(y2), "+v"(x2));
    u32x4 f0 = {x1, x2, y1, y2};
    bf16x8 pa0 = __builtin_bit_cast(bf16x8, f0);
    unsigned int x3 = cvtpk(p[8], p[9]),   x4 = cvtpk(p[10], p[11]);
    unsigned int y3 = cvtpk(p[12], p[13]), y4 = cvtpk(p[14], p[15]);
    asm volatile("v_permlane32_swap_b32 %0, %1" : "+v"(y3), "+v"(x3));
    asm volatile("v_permlane32_swap_b32 %0, %1" : "+v"(y4), "+v"(x4));
    u32x4 f1 = {x3, x4, y3, y4};
    bf16x8 pa1 = __builtin_bit_cast(bf16x8, f1);

    // --- PV: A=P (regs), B=V from LDS ---
    __builtin_amdgcn_s_setprio(1);
#pragma unroll
    for (int kc = 0; kc < 2; ++kc) {
      bf16x8 pa = kc ? pa1 : pa0;
      bf16x8 va = *(const bf16x8*)(Vb + c32 * 128 + vchunk[kc]);
      bf16x8 vb = *(const bf16x8*)(Vb + (32 + c32) * 128 + vchunk[kc]);
      o0 = __builtin_amdgcn_mfma_f32_32x32x16_bf16(pa, va, o0, 0, 0, 0);
      o1 = __builtin_amdgcn_mfma_f32_32x32x16_bf16(pa, vb, o1, 0, 0, 0);
    }
    __builtin_amdgcn_s_setprio(0);

    if (!last) {
      asm volatile("" ::: "memory");      // all reads issued before the barrier
      __builtin_amdgcn_s_barrier();       // reads of buf cur done in all waves
      asm volatile("" ::: "memory");
    }
  };

  for (int kbi = 0; kbi < 30; kbi += 2) {
    step(kbi, 0, false);
    step(kbi + 1, 1, false);
  }
  step(30, 0, false);
  step(31, 1, true);

  // ---- epilogue: combine k-half waves via LDS, normalize, write ----
  srun += __shfl_xor(srun, 32);           // full 32-k sum per q=c32
  __syncthreads();                        // all K/V reads done; Ks reusable
  float* olds = (float*)Ks;               // 16KB: [wq][32 q][64 d]
  if (wk == 1) {
#pragma unroll
    for (int reg = 0; reg < 16; ++reg) {
      int qrow = (reg & 3) + 8 * (reg >> 2) + 4 * h;
      olds[wq * 2048 + qrow * 64 + c32]      = o0[reg];
      olds[wq * 2048 + qrow * 64 + 32 + c32] = o1[reg];
    }
    srun_l[wq * 32 + c32] = srun;
  }
  __syncthreads();
  if (wk == 0) {
    float stot = srun + srun_l[wq * 32 + c32];
    int b = bh >> 3, hd = bh & 7;
#pragma unroll
    for (int reg = 0; reg < 16; ++reg) {
      int qrow = (reg & 3) + 8 * (reg >> 2) + 4 * h;
      float inv = 1.f / __shfl(stot, qrow);
      float s0 = o0[reg] + olds[wq * 2048 + qrow * 64 + c32];
      float s1 = o1[reg] + olds[wq * 2048 + qrow * 64 + 32 + c32];
      int qg2 = q0 + wq * 32 + qrow;
      size_t base = ((size_t)(b * 2048 + qg2)) * 512 + hd * 64;
      ctx[base + c32]      = (__bf16)(s0 * inv);
      ctx[base + 32 + c32] = (__bf16)(s1 * inv);
    }
  }
}

// ---------------- LayerNorm (residual add fused) ----------------
// IN1F32: in1 is f32 (else bf16). WF: write f32 out (else bf16 out).
// IN3: add a third input (bf16 partial from K-split GEMM).
template<bool IN1F32, bool WF, bool IN3>
__global__ __launch_bounds__(256)
void ln_k(const float* __restrict__ in1f, const __bf16* __restrict__ in1b,
          const __bf16* __restrict__ in2, const __bf16* __restrict__ in3,
          const float* __restrict__ gam, const float* __restrict__ bet,
          float* __restrict__ outf, __bf16* __restrict__ outb) {
  int w = threadIdx.x >> 6, lane = threadIdx.x & 63;
  int row = blockIdx.x * 4 + w;
  size_t base = (size_t)row * 512 + lane * 8;
  float a[8];
  if (IN1F32) {
    float4 a0 = *(const float4*)(in1f + base);
    float4 a1 = *(const float4*)(in1f + base + 4);
    a[0] = a0.x; a[1] = a0.y; a[2] = a0.z; a[3] = a0.w;
    a[4] = a1.x; a[5] = a1.y; a[6] = a1.z; a[7] = a1.w;
  } else {
    bf16x8 av = *(const bf16x8*)(in1b + base);
#pragma unroll
    for (int k = 0; k < 8; ++k) a[k] = (float)av[k];
  }
  bf16x8 bv = *(const bf16x8*)(in2 + base);
  float x[8];
#pragma unroll
  for (int k = 0; k < 8; ++k) x[k] = a[k] + (float)bv[k];
  if (IN3) {
    bf16x8 cv = *(const bf16x8*)(in3 + base);
#pragma unroll
    for (int k = 0; k < 8; ++k) x[k] += (float)cv[k];
  }
  float s1 = 0.f, s2 = 0.f;
#pragma unroll
  for (int k = 0; k < 8; ++k) { s1 += x[k]; s2 += x[k] * x[k]; }
#pragma unroll
  for (int m = 1; m < 64; m <<= 1) { s1 += __shfl_xor(s1, m); s2 += __shfl_xor(s2, m); }
  float mu = s1 * (1.f / 512.f);
  float var = s2 * (1.f / 512.f) - mu * mu;
  float rs = rsqrtf(var + 1e-5f);
  float4 g0 = *(const float4*)(gam + lane * 8);
  float4 g1 = *(const float4*)(gam + lane * 8 + 4);
  float4 e0 = *(const float4*)(bet + lane * 8);
  float4 e1 = *(const float4*)(bet + lane * 8 + 4);
  float gg[8] = {g0.x, g0.y, g0.z, g0.w, g1.x, g1.y, g1.z, g1.w};
  float bb[8] = {e0.x, e0.y, e0.z, e0.w, e1.x, e1.y, e1.z, e1.w};
  float y[8];
#pragma unroll
  for (int k = 0; k < 8; ++k) y[k] = (x[k] - mu) * rs * gg[k] + bb[k];
  if (WF) {
    float4 o0 = {y[0], y[1], y[2], y[3]};
    float4 o1 = {y[4], y[5], y[6], y[7]};
    *(float4*)(outf + base) = o0;
    *(float4*)(outf + base + 4) = o1;
  } else {
    union { __bf16 hh[8]; uint4 u; } pk;
#pragma unroll
    for (int k = 0; k < 8; ++k) pk.hh[k] = (__bf16)y[k];
    *(uint4*)(outb + base) = pk.u;
  }
}

extern "C" void kernel_launch(void* const* d_in, const int* in_sizes, int n_in,
                              void* d_out, int out_size, void* d_ws, size_t ws_size,
                              hipStream_t stream) {
  (void)in_sizes; (void)n_in; (void)out_size;
  const float* x    = (const float*)d_in[0];
  const float* Wqkv = (const float*)d_in[1];
  const float* bqkv = (const float*)d_in[2];
  const float* Wo   = (const float*)d_in[3];
  const float* bo   = (const float*)d_in[4];
  const float* g1   = (const float*)d_in[5];
  const float* be1  = (const float*)d_in[6];
  const float* W1   = (const float*)d_in[7];
  const float* b1   = (const float*)d_in[8];
  const float* W2   = (const float*)d_in[9];
  const float* b2   = (const float*)d_in[10];
  const float* g2   = (const float*)d_in[11];
  const float* be2  = (const float*)d_in[12];
  float* out = (float*)d_out;

  char* ws = (char*)d_ws;
  size_t off = 0;
  auto alloc = [&](size_t bytes) {
    char* p = ws + off;
    off += (bytes + 255) & ~(size_t)255;
    return p;
  };
  __bf16* xb    = (__bf16*)alloc((size_t)M_ * 512 * 2);
  __bf16* wqkvt = (__bf16*)alloc((size_t)1536 * 512 * 2);
  __bf16* wot   = (__bf16*)alloc((size_t)512 * 512 * 2);
  __bf16* w1t   = (__bf16*)alloc((size_t)2048 * 512 * 2);
  __bf16* w2t   = (__bf16*)alloc((size_t)512 * 2048 * 2);
  __bf16* qbuf  = (__bf16*)alloc((size_t)32 * 2048 * 64 * 2);
  __bf16* kbuf  = (__bf16*)alloc((size_t)32 * 2048 * 64 * 2);
  __bf16* vtbuf = (__bf16*)alloc((size_t)32 * 64 * 2048 * 2);
  __bf16* ctxb  = (__bf16*)alloc((size_t)M_ * 512 * 2);
  __bf16* part0 = (__bf16*)alloc((size_t)M_ * 512 * 2);   // K-split partial 0
  __bf16* part1 = (__bf16*)alloc((size_t)M_ * 512 * 2);   // K-split partial 1
  __bf16* y1b   = (__bf16*)alloc((size_t)M_ * 512 * 2);
  __bf16* h1    = (__bf16*)alloc((size_t)M_ * 2048 * 2);
  if (off > ws_size) return;  // workspace too small: fail loudly (wrong output)

  cvt_x_k<<<4096, 256, 0, stream>>>(x, xb);
  tcvt_all_k<<<768, 256, 0, stream>>>(Wqkv, Wo, W1, W2, wqkvt, wot, w1t, w2t);

  gemm_k<0, 1536, 512, 128><<<768, 256, 0, stream>>>(xb, wqkvt, bqkv, nullptr, nullptr,
                                                     qbuf, kbuf, vtbuf);
  attn_k<<<1024, 256, 0, stream>>>(qbuf, kbuf, vtbuf, ctxb);
  // wo: 2-way K-split, partials combined in LN1
  gemm_k<3, 512, 512, 64, 2><<<1024, 256, 0, stream>>>(ctxb, wot, bo, nullptr, part0,
                                                       part1, nullptr, nullptr);
  ln_k<true, false, true><<<2048, 256, 0, stream>>>(x, nullptr, part0, part1, g1, be1,
                                                    nullptr, y1b);
  gemm_k<2, 2048, 512, 128><<<1024, 256, 0, stream>>>(y1b, w1t, b1, nullptr, h1,
                                                      nullptr, nullptr, nullptr);
  // ffn2: 2-way K-split, partials combined in LN2 (part0/1 dead after LN1)
  gemm_k<3, 512, 2048, 64, 2><<<1024, 256, 0, stream>>>(h1, w2t, b2, nullptr, part0,
                                                        part1, nullptr, nullptr);
  ln_k<false, true, true><<<2048, 256, 0, stream>>>(nullptr, y1b, part0, part1, g2, be2,
                                                    out, nullptr);
}